// Round 1
// 93.924 us; speedup vs baseline: 1.0879x; 1.0879x over previous
//
#include <hip/hip_runtime.h>
#include <math.h>

#define PI_F 3.14159265358979323846f

struct c32 { float x, y; };

// ---- 4-qubit state: 16 amps, wire w = bit (3-w) of index ----

// Rot gate in SU(2)-reduced form: matrix [[A, -conj(C)],[C, conj(A)]]
__device__ __forceinline__ void apply_rot_red(c32* s, const int w,
                                              float Ax, float Ay, float Cx, float Cy){
  const int m = 8 >> w;
  #pragma unroll
  for (int i = 0; i < 16; i++){
    if (i & m) continue;
    c32 a = s[i], b = s[i | m];
    s[i].x     = Ax*a.x - Ay*a.y - Cx*b.x - Cy*b.y;
    s[i].y     = Ax*a.y + Ay*a.x - Cx*b.y + Cy*b.x;
    s[i | m].x = Cx*a.x - Cy*a.y + Ax*b.x + Ay*b.y;
    s[i | m].y = Cx*a.y + Cy*a.x + Ax*b.y - Ay*b.x;
  }
}

// fused CRX(t) followed by CNOT on (control wa, target wb)
__device__ __forceinline__ void apply_crxnot(c32* s, const int wa, const int wb,
                                             float c, float sn){
  const int ma = 8 >> wa, mb = 8 >> wb;
  #pragma unroll
  for (int i = 0; i < 16; i++){
    if (!(i & ma) || (i & mb)) continue;
    c32 u = s[i], v = s[i | mb];
    s[i]      = { c*v.x + sn*u.y, c*v.y - sn*u.x };   // CNOT swap folded in
    s[i | mb] = { c*u.x + sn*v.y, c*u.y - sn*v.x };
  }
}

// gp: 8 gates x 8 floats {A.x,A.y,C.x,C.y,crx_c,crx_s,pad,pad} (LDS, wave-uniform reads)
__device__ __forceinline__ void sim_initqkv(c32* s, const float* gp){
  constexpr int pa[8] = {0,1,2,3,0,1,2,3};
  constexpr int pb[8] = {1,2,3,0,3,0,1,2};
  #pragma unroll
  for (int g = 0; g < 8; g++){
    const float* q = gp + 8*g;
    apply_rot_red(s, pa[g], q[0], q[1], q[2], q[3]);
    apply_crxnot(s, pa[g], pb[g], q[4], q[5]);
  }
}

// RX(x)|0000> is a product state: amp[i] = (prod of c/s) * (-i)^popcount(i)
__device__ __forceinline__ void build_rx(c32* s, const float* cw, const float* sw){
  float m01[4] = { cw[0]*cw[1], cw[0]*sw[1], sw[0]*cw[1], sw[0]*sw[1] };
  float m23[4] = { cw[2]*cw[3], cw[2]*sw[3], sw[2]*cw[3], sw[2]*sw[3] };
  #pragma unroll
  for (int i = 0; i < 16; i++){
    float mag = m01[(i >> 2) & 3] * m23[i & 3];
    const int pc = __popc(i) & 3;
    s[i] = (pc == 0) ? c32{ mag, 0.f } :
           (pc == 1) ? c32{ 0.f, -mag } :
           (pc == 2) ? c32{ -mag, 0.f } : c32{ 0.f, mag };
  }
}

__device__ __forceinline__ float fast_tanh(float x){
  float e = __expf(2.f * x);
  return 1.f - 2.f * __builtin_amdgcn_rcpf(e + 1.f);
}

// ============================================================================
// Setup kernel (1 block, 64 threads): computes the grid-uniform data once.
// ws layout: [0..63] q gates, [64..127] v gates, [128..131] cxk
// ============================================================================
__global__ __launch_bounds__(64, 1) void qc_setup(
    const float* __restrict__ q_rot, const float* __restrict__ k_rot,
    const float* __restrict__ v_rot,
    const float* __restrict__ q_crx, const float* __restrict__ k_crx,
    const float* __restrict__ v_crx,
    float* __restrict__ ws){

  __shared__ float gates[3 * 64];      // [q | k | v], 8 gates x 8 floats each
  const int t = threadIdx.x;

  if (t < 24){
    const int grp = t >> 3, g = t & 7;
    const float* rotp = grp == 0 ? q_rot : (grp == 1 ? k_rot : v_rot);
    const float* crxp = grp == 0 ? q_crx : (grp == 1 ? k_crx : v_crx);
    float phi = rotp[3*g], th = rotp[3*g+1], om = rotp[3*g+2];
    float c, s, ca, sa, cb, sb;
    __sincosf(0.5f*th,       &s,  &c);
    __sincosf(0.5f*(phi+om), &sa, &ca);
    __sincosf(0.5f*(phi-om), &sb, &cb);
    float cc, cs; __sincosf(0.5f*crxp[g], &cs, &cc);
    float* dst = &gates[64*grp + 8*g];
    dst[0] = c*ca; dst[1] = -c*sa; dst[2] = s*cb; dst[3] = -s*sb;
    dst[4] = cc;   dst[5] = cs;
    dst[6] = 0.f;  dst[7] = 0.f;
  }
  __syncthreads();

  // k-circuit expX constants (batch-uniform; all lanes compute in lockstep)
  c32 ks[16];
  #pragma unroll
  for (int i = 0; i < 16; i++) ks[i] = { 0.f, 0.f };
  ks[0] = { 1.f, 0.f };
  sim_initqkv(ks, &gates[64]);
  float cxk[4];
  #pragma unroll
  for (int w = 0; w < 4; w++){
    const int m = 8 >> w;
    float r = 0.f;
    #pragma unroll
    for (int i = 0; i < 16; i++){
      if (i & m) continue;
      r += ks[i].x*ks[i|m].x + ks[i].y*ks[i|m].y;
    }
    cxk[w] = 2.f * r;
  }

  ws[t]      = gates[t];         // q gates
  ws[64 + t] = gates[128 + t];   // v gates
  if (t < 4) ws[128 + t] = cxk[t];
}

// ============================================================================
// Main kernel: block = 128 threads = 2 waves per 64 samples.
//   wave 0: q-circuit -> scores -> RZ half-angles (handoff via LDS)
//   wave 1: v-circuit -> Z-strings, then phases + X-strings + LN/GELU/head
// Within-wave lane-splitting would serialize via exec mask; the split must be
// across waves so the two sims land on different SIMDs and truly overlap.
// ============================================================================
#define LDS_STRIDE 97   // 97 % 32 == 1 -> only 2-way bank aliasing on row reads (free)

__global__ __launch_bounds__(128, 1) void qc_main(
    const float* __restrict__ x1,
    const float* __restrict__ pre_w, const float* __restrict__ pre_b,
    const float* __restrict__ gws,   // from qc_setup
    const float* __restrict__ ln_w, const float* __restrict__ ln_b,
    const float* __restrict__ head_w, const float* __restrict__ head_b,
    float* __restrict__ out, int B){

  __shared__ float xs[64 * LDS_STRIDE];
  __shared__ float gl[132];        // [0..63] q gates, [64..127] v gates, [128..131] cxk
  __shared__ float scr[8][64];     // handoff: [2w][lane]=cos(th/2), [2w+1][lane]=sin(th/2)

  const int t    = threadIdx.x;
  const int lane = t & 63;
  const int wid  = t >> 6;
  const int base = blockIdx.x * 64;

  // ---- load grid-uniform gate data ----
  if (t < 128) gl[t] = gws[t];
  if (t < 4)   gl[128 + t] = gws[128 + t];

  // ---- stage 64x96 slice of x1 into LDS (coalesced float4, 128 threads) ----
  {
    int rem = B - base; if (rem > 64) rem = 64;
    const int nf4 = rem * 24;
    const float4* src = (const float4*)(x1 + (long)base * 96);
    #pragma unroll
    for (int k = 0; k < 12; k++){
      int g = t + 128*k;
      if (g < nf4){
        float4 v = src[g];
        int f = 4*g;
        int r = f / 96, cidx = f - 96*r;
        float* d = &xs[r*LDS_STRIDE + cidx];
        d[0]=v.x; d[1]=v.y; d[2]=v.z; d[3]=v.w;
      }
    }
  }
  __syncthreads();

  // ---- x = row @ pre_w.T + pre_b (both waves; duplicated but parallel) ----
  float xw[4];
  {
    float a0 = pre_b[0], a1 = pre_b[1], a2 = pre_b[2], a3 = pre_b[3];
    const float* row = &xs[lane * LDS_STRIDE];
    #pragma unroll
    for (int j = 0; j < 96; j++){
      float v = row[j];
      a0 += v * pre_w[j];
      a1 += v * pre_w[96  + j];
      a2 += v * pre_w[192 + j];
      a3 += v * pre_w[288 + j];
    }
    xw[0]=a0; xw[1]=a1; xw[2]=a2; xw[3]=a3;
  }

  float cw[4], sw[4];
  #pragma unroll
  for (int w = 0; w < 4; w++) __sincosf(0.5f*xw[w], &sw[w], &cw[w]);

  c32 st[16];
  build_rx(st, cw, sw);

  float o[8];      // wave 1 outputs (o[0..3] filled pre-barrier)

  if (wid == 0){
    // ---- q role: phi = U_q RX(x)|0>; post-RX layer folded into expectations ----
    sim_initqkv(st, &gl[0]);
    float p[16];
    #pragma unroll
    for (int i = 0; i < 16; i++) p[i] = st[i].x*st[i].x + st[i].y*st[i].y;
    #pragma unroll
    for (int w = 0; w < 4; w++){
      const int m = 8 >> w;
      float sz = 0.f, sx = 0.f, sy = 0.f;
      #pragma unroll
      for (int i = 0; i < 16; i++) sz += (i & m) ? -p[i] : p[i];
      #pragma unroll
      for (int i = 0; i < 16; i++){
        if (i & m) continue;
        c32 a = st[i], b = st[i|m];
        sx += a.x*b.x + a.y*b.y;
        sy += a.x*b.y - a.y*b.x;
      }
      // RX(theta)^dag Z RX(theta) = cos(th) Z + sin(th) Y ; X invariant under RX
      float cth = 1.f - 2.f*sw[w]*sw[w];
      float sth = 2.f*sw[w]*cw[w];
      float z   = cth*sz + sth*(2.f*sy);
      float xm  = (2.f*sx) * gl[128 + w];   // cxk
      float score = sqrtf(z*z + xm*xm);
      float th = fast_tanh(score) * PI_F;
      float srv, crv; __sincosf(0.5f*th, &srv, &crv);
      scr[2*w][lane]     = crv;
      scr[2*w + 1][lane] = srv;
    }
  } else {
    // ---- v role (pre-barrier part): phi = U_v RX(x)|0>; Z-strings from |amp|^2 ----
    sim_initqkv(st, &gl[64]);
    float p[16];
    #pragma unroll
    for (int i = 0; i < 16; i++) p[i] = st[i].x*st[i].x + st[i].y*st[i].y;
    // Z through CNOT chain -> Z-strings (diagonal; RZ phases cancel)
    constexpr int zm[4] = {8, 12, 14, 15};
    #pragma unroll
    for (int w = 0; w < 4; w++){
      float r = 0.f;
      #pragma unroll
      for (int i = 0; i < 16; i++)
        r += (__popc(i & zm[w]) & 1) ? -p[i] : p[i];
      o[w] = r;
    }
  }

  __syncthreads();   // scr handoff; wave 0 is done after this

  if (wid == 1){
    float cr[4], sr[4];
    #pragma unroll
    for (int w = 0; w < 4; w++){
      cr[w] = scr[2*w][lane];
      sr[w] = scr[2*w + 1][lane];
    }
    // apply RZ phases: amp[i] *= prod_w e^{+-i th_w/2}
    c32 ph01[4], ph23[4];
    ph01[0] = { cr[0]*cr[1] - sr[0]*sr[1], -(cr[0]*sr[1] + sr[0]*cr[1]) };
    ph01[1] = { cr[0]*cr[1] + sr[0]*sr[1],   cr[0]*sr[1] - sr[0]*cr[1] };
    ph01[2] = { ph01[1].x, -ph01[1].y };
    ph01[3] = { ph01[0].x, -ph01[0].y };
    ph23[0] = { cr[2]*cr[3] - sr[2]*sr[3], -(cr[2]*sr[3] + sr[2]*cr[3]) };
    ph23[1] = { cr[2]*cr[3] + sr[2]*sr[3],   cr[2]*sr[3] - sr[2]*cr[3] };
    ph23[2] = { ph23[1].x, -ph23[1].y };
    ph23[3] = { ph23[0].x, -ph23[0].y };
    #pragma unroll
    for (int i = 0; i < 16; i++){
      c32 a = st[i], f = ph01[(i >> 2) & 3], g2 = ph23[i & 3];
      c32 b = { a.x*f.x - a.y*f.y, a.x*f.y + a.y*f.x };
      st[i] = { b.x*g2.x - b.y*g2.y, b.x*g2.y + b.y*g2.x };
    }
    // X through CNOT chain -> X-strings with masks {12,6,3,1}
    constexpr int xmk[4] = {12, 6, 3, 1};
    constexpr int hb[4]  = {8, 4, 2, 1};
    #pragma unroll
    for (int w = 0; w < 4; w++){
      float r = 0.f;
      #pragma unroll
      for (int i = 0; i < 16; i++){
        if (i & hb[w]) continue;
        const int j = i ^ xmk[w];
        r += st[i].x*st[j].x + st[i].y*st[j].y;
      }
      o[4 + w] = 2.f * r;
    }

    // ---- LayerNorm(8) -> tanh-GELU -> head ----
    float mu = 0.f;
    #pragma unroll
    for (int j = 0; j < 8; j++) mu += o[j];
    mu *= 0.125f;
    float var = 0.f;
    #pragma unroll
    for (int j = 0; j < 8; j++){ float d = o[j] - mu; var += d*d; }
    var *= 0.125f;
    float inv = rsqrtf(var + 1e-5f);
    float h0 = head_b[0], h1 = head_b[1];
    #pragma unroll
    for (int j = 0; j < 8; j++){
      float y = (o[j] - mu) * inv * ln_w[j] + ln_b[j];
      float u = 0.7978845608f * (y + 0.044715f*y*y*y);
      float g = 0.5f * y * (1.f + fast_tanh(u));
      h0 += g * head_w[j];
      h1 += g * head_w[8 + j];
    }

    const int sid = base + lane;
    if (sid < B){
      float2 r2; r2.x = h0; r2.y = h1;
      ((float2*)out)[sid] = r2;
    }
  }
}

extern "C" void kernel_launch(void* const* d_in, const int* in_sizes, int n_in,
                              void* d_out, int out_size, void* d_ws, size_t ws_size,
                              hipStream_t stream) {
  const float* x1     = (const float*)d_in[0];
  const float* pre_w  = (const float*)d_in[1];
  const float* pre_b  = (const float*)d_in[2];
  const float* q_rot  = (const float*)d_in[3];
  const float* k_rot  = (const float*)d_in[4];
  const float* v_rot  = (const float*)d_in[5];
  const float* q_crx  = (const float*)d_in[6];
  const float* k_crx  = (const float*)d_in[7];
  const float* v_crx  = (const float*)d_in[8];
  const float* ln_w   = (const float*)d_in[9];
  const float* ln_b   = (const float*)d_in[10];
  const float* head_w = (const float*)d_in[11];
  const float* head_b = (const float*)d_in[12];
  float* out = (float*)d_out;
  float* ws  = (float*)d_ws;
  (void)ws_size; (void)n_in; (void)out_size;

  const int B = in_sizes[0] / 96;
  const int nb = (B + 63) / 64;

  qc_setup<<<1, 64, 0, stream>>>(q_rot, k_rot, v_rot, q_crx, k_crx, v_crx, ws);
  qc_main<<<nb, 128, 0, stream>>>(x1, pre_w, pre_b, ws,
                                  ln_w, ln_b, head_w, head_b, out, B);
}

// Round 2
// 89.374 us; speedup vs baseline: 1.1432x; 1.0509x over previous
//
#include <hip/hip_runtime.h>
#include <math.h>

#define PI_F 3.14159265358979323846f

struct c32 { float x, y; };

// ---------------------------------------------------------------------------
// quad-lane DPP helpers (all cross-lane traffic is intra-quad quad_perm DPP)
// ---------------------------------------------------------------------------
#define DPP_X1 0xB1   // quad_perm [1,0,3,2]  lane ^ 1
#define DPP_X2 0x4E   // quad_perm [2,3,0,1]  lane ^ 2
#define DPP_X3 0x1B   // quad_perm [3,2,1,0]  lane ^ 3

template<int CTRL>
__device__ __forceinline__ float dppf(float v){
  return __int_as_float(__builtin_amdgcn_update_dpp(
      0, __float_as_int(v), CTRL, 0xF, 0xF, true));
}

__device__ __forceinline__ float qred(float v){   // quad butterfly sum
  v += dppf<DPP_X1>(v);
  v += dppf<DPP_X2>(v);
  return v;
}

__device__ __forceinline__ float sel4(bool b0, bool b1,
                                      float v0, float v1, float v2, float v3){
  float lo = b0 ? v1 : v0;
  float hi = b0 ? v3 : v2;
  return b1 ? hi : lo;
}

__device__ __forceinline__ float fast_tanh(float x){
  float e = __expf(2.f * x);
  return 1.f - 2.f * __builtin_amdgcn_rcpf(e + 1.f);
}

// ---------------------------------------------------------------------------
// 4-qubit state split across a quad: lane q (= lane&3) holds amps (q<<2)|k,
// k = 0..3.  Wire w -> amp-index bit (3-w):
//   wire0 -> q bit1 (lane^2), wire1 -> q bit0 (lane^1),
//   wire2 -> k bit1 (local),  wire3 -> k bit0 (local)
// ---------------------------------------------------------------------------

// Rot [[A, -conj(C)],[C, conj(A)]] on a lane wire.
// low side: new = A*u - conj(C)*v ; high side: new = conj(A)*u + C*v
// -> P = (Ax, sgn*Ay), Q = (-sgn*Cx, Cy), sgn = +1 low / -1 high
template<int XM>
__device__ __forceinline__ void rot_lane(c32* a, float Ax, float Ay,
                                         float Cx, float Cy, float sgn){
  c32 r[4];
  #pragma unroll
  for (int k = 0; k < 4; k++){ r[k].x = dppf<XM>(a[k].x); r[k].y = dppf<XM>(a[k].y); }
  float Py = Ay * sgn, Qx = -Cx * sgn;
  #pragma unroll
  for (int k = 0; k < 4; k++){
    float nx = Ax*a[k].x - Py*a[k].y + Qx*r[k].x - Cy*r[k].y;
    float ny = Ax*a[k].y + Py*a[k].x + Qx*r[k].y + Cy*r[k].x;
    a[k].x = nx; a[k].y = ny;
  }
}

// Rot on a local wire (pairs (k, k|MB)) -- same algebra as the scalar kernel
template<int MB>
__device__ __forceinline__ void rot_local(c32* a, float Ax, float Ay,
                                          float Cx, float Cy){
  #pragma unroll
  for (int k = 0; k < 4; k++){
    if (k & MB) continue;
    c32 u = a[k], v = a[k|MB];
    a[k].x    = Ax*u.x - Ay*u.y - Cx*v.x - Cy*v.y;
    a[k].y    = Ax*u.y + Ay*u.x - Cx*v.y + Cy*v.x;
    a[k|MB].x = Cx*u.x - Cy*u.y + Ax*v.x + Ay*v.y;
    a[k|MB].y = Cx*u.y + Cy*u.x + Ax*v.y - Ay*v.x;
  }
}

// fused CRX+CNOT primitive: each slot <- c*other + sn*(own.y, -own.x)
__device__ __forceinline__ void crx_pair(c32& u, c32& v, float c, float sn){
  c32 uo = u, vo = v;
  u.x = c*vo.x + sn*uo.y;  u.y = c*vo.y - sn*uo.x;
  v.x = c*uo.x + sn*vo.y;  v.y = c*uo.y - sn*vo.x;
}

// control on lane wire (active per lane), target local: pairs k <-> k^KM
template<int KM>
__device__ __forceinline__ void crx_lanectl_local(c32* a, float c, float sn, bool act){
  c32 n[4];
  #pragma unroll
  for (int k = 0; k < 4; k++){
    n[k].x = c*a[k^KM].x + sn*a[k].y;
    n[k].y = c*a[k^KM].y - sn*a[k].x;
  }
  #pragma unroll
  for (int k = 0; k < 4; k++){
    a[k].x = act ? n[k].x : a[k].x;
    a[k].y = act ? n[k].y : a[k].y;
  }
}

// control on local wire (amps K0,K1 of every lane), target lane wire XM
template<int XM, int K0, int K1>
__device__ __forceinline__ void crx_localctl_lane(c32* a, float c, float sn){
  float rx0 = dppf<XM>(a[K0].x), ry0 = dppf<XM>(a[K0].y);
  float rx1 = dppf<XM>(a[K1].x), ry1 = dppf<XM>(a[K1].y);
  float u0x = a[K0].x, u0y = a[K0].y, u1x = a[K1].x, u1y = a[K1].y;
  a[K0].x = c*rx0 + sn*u0y;  a[K0].y = c*ry0 - sn*u0x;
  a[K1].x = c*rx1 + sn*u1y;  a[K1].y = c*ry1 - sn*u1x;
}

// control and target both lane wires
template<int XM>
__device__ __forceinline__ void crx_lane_lane(c32* a, float c, float sn, bool act){
  #pragma unroll
  for (int k = 0; k < 4; k++){
    float rx = dppf<XM>(a[k].x), ry = dppf<XM>(a[k].y);
    float nx = c*rx + sn*a[k].y;
    float ny = c*ry - sn*a[k].x;
    a[k].x = act ? nx : a[k].x;
    a[k].y = act ? ny : a[k].y;
  }
}

// full initQKV ladder; gp = 8 gates x 8 floats {Ax,Ay,Cx,Cy,c,s,_,_}
// pairs: (0,1)(1,2)(2,3)(3,0)(0,3)(1,0)(2,1)(3,2)
__device__ __forceinline__ void sim4(c32* a, const float* __restrict__ gp,
                                     float sgnW0, float sgnW1, bool qb0, bool qb1){
  rot_lane<DPP_X2>(a, gp[0],  gp[1],  gp[2],  gp[3],  sgnW0);   // Rot w0
  crx_lane_lane<DPP_X1>(a, gp[4], gp[5], qb1);                  // CRX(0,1): act qb1, pair lane^1
  rot_lane<DPP_X1>(a, gp[8],  gp[9],  gp[10], gp[11], sgnW1);   // Rot w1
  crx_lanectl_local<2>(a, gp[12], gp[13], qb0);                 // CRX(1,2): act qb0, k^2
  rot_local<2>(a, gp[16], gp[17], gp[18], gp[19]);              // Rot w2
  crx_pair(a[2], a[3], gp[20], gp[21]);                         // CRX(2,3)
  rot_local<1>(a, gp[24], gp[25], gp[26], gp[27]);              // Rot w3
  crx_localctl_lane<DPP_X2,1,3>(a, gp[28], gp[29]);             // CRX(3,0): amps{1,3}, lane^2
  rot_lane<DPP_X2>(a, gp[32], gp[33], gp[34], gp[35], sgnW0);   // Rot w0
  crx_lanectl_local<1>(a, gp[36], gp[37], qb1);                 // CRX(0,3): act qb1, k^1
  rot_lane<DPP_X1>(a, gp[40], gp[41], gp[42], gp[43], sgnW1);   // Rot w1
  crx_lane_lane<DPP_X2>(a, gp[44], gp[45], qb0);                // CRX(1,0): act qb0, lane^2
  rot_local<2>(a, gp[48], gp[49], gp[50], gp[51]);              // Rot w2
  crx_localctl_lane<DPP_X1,2,3>(a, gp[52], gp[53]);             // CRX(2,1): amps{2,3}, lane^1
  rot_local<1>(a, gp[56], gp[57], gp[58], gp[59]);              // Rot w3
  crx_pair(a[1], a[3], gp[60], gp[61]);                         // CRX(3,2)
}

// RX(x)|0000> product state, per-lane slice: amp = mag * (-i)^popc(i)
__device__ __forceinline__ void build_rx4(c32* a, const float* cw, const float* sw,
                                          int q, bool qb0, bool qb1){
  float m01 = (qb1 ? sw[0] : cw[0]) * (qb0 ? sw[1] : cw[1]);
  float g0 = m01 * (cw[2]*cw[3]);
  float g1 = m01 * (cw[2]*sw[3]);
  float g2 = m01 * (sw[2]*cw[3]);
  float g3 = m01 * (sw[2]*sw[3]);
  // base phase (-i)^popc(q): q=0 -> (1,0); q=1,2 -> (0,-1); q=3 -> (-1,0)
  float bx = (q == 0) ? 1.f : (q == 3) ? -1.f : 0.f;
  float by = (q == 1 || q == 2) ? -1.f : 0.f;
  a[0].x =  g0*bx;  a[0].y =  g0*by;   // k=0: *1
  a[1].x =  g1*by;  a[1].y = -g1*bx;   // k=1: *(-i)
  a[2].x =  g2*by;  a[2].y = -g2*bx;   // k=2: *(-i)
  a[3].x = -g3*bx;  a[3].y = -g3*by;   // k=3: *(-1)
}

// ============================================================================
// Setup kernel (1 block, 64 threads): grid-uniform gate matrices + cxk.
// ws: [0..63] q gates, [64..127] v gates, [128..131] cxk
// ============================================================================
__device__ __forceinline__ void apply_rot_red16(c32* s, const int w,
                                                float Ax, float Ay, float Cx, float Cy){
  const int m = 8 >> w;
  #pragma unroll
  for (int i = 0; i < 16; i++){
    if (i & m) continue;
    c32 a = s[i], b = s[i | m];
    s[i].x     = Ax*a.x - Ay*a.y - Cx*b.x - Cy*b.y;
    s[i].y     = Ax*a.y + Ay*a.x - Cx*b.y + Cy*b.x;
    s[i | m].x = Cx*a.x - Cy*a.y + Ax*b.x + Ay*b.y;
    s[i | m].y = Cx*a.y + Cy*a.x + Ax*b.y - Ay*b.x;
  }
}

__device__ __forceinline__ void apply_crxnot16(c32* s, const int wa, const int wb,
                                               float c, float sn){
  const int ma = 8 >> wa, mb = 8 >> wb;
  #pragma unroll
  for (int i = 0; i < 16; i++){
    if (!(i & ma) || (i & mb)) continue;
    c32 u = s[i], v = s[i | mb];
    s[i]      = { c*v.x + sn*u.y, c*v.y - sn*u.x };
    s[i | mb] = { c*u.x + sn*v.y, c*u.y - sn*v.x };
  }
}

__global__ __launch_bounds__(64, 1) void qc_setup(
    const float* __restrict__ q_rot, const float* __restrict__ k_rot,
    const float* __restrict__ v_rot,
    const float* __restrict__ q_crx, const float* __restrict__ k_crx,
    const float* __restrict__ v_crx,
    float* __restrict__ ws){

  __shared__ float gates[3 * 64];
  const int t = threadIdx.x;

  if (t < 24){
    const int grp = t >> 3, g = t & 7;
    const float* rotp = grp == 0 ? q_rot : (grp == 1 ? k_rot : v_rot);
    const float* crxp = grp == 0 ? q_crx : (grp == 1 ? k_crx : v_crx);
    float phi = rotp[3*g], th = rotp[3*g+1], om = rotp[3*g+2];
    float c, s, ca, sa, cb, sb;
    __sincosf(0.5f*th,       &s,  &c);
    __sincosf(0.5f*(phi+om), &sa, &ca);
    __sincosf(0.5f*(phi-om), &sb, &cb);
    float cc, cs; __sincosf(0.5f*crxp[g], &cs, &cc);
    float* dst = &gates[64*grp + 8*g];
    dst[0] = c*ca; dst[1] = -c*sa; dst[2] = s*cb; dst[3] = -s*sb;
    dst[4] = cc;   dst[5] = cs;
    dst[6] = 0.f;  dst[7] = 0.f;
  }
  __syncthreads();

  // k-circuit expX constants (all lanes compute in lockstep)
  c32 ks[16];
  #pragma unroll
  for (int i = 0; i < 16; i++) ks[i] = { 0.f, 0.f };
  ks[0] = { 1.f, 0.f };
  {
    constexpr int pa[8] = {0,1,2,3,0,1,2,3};
    constexpr int pb[8] = {1,2,3,0,3,0,1,2};
    #pragma unroll
    for (int g = 0; g < 8; g++){
      const float* qq = &gates[64 + 8*g];
      apply_rot_red16(ks, pa[g], qq[0], qq[1], qq[2], qq[3]);
      apply_crxnot16(ks, pa[g], pb[g], qq[4], qq[5]);
    }
  }
  float cxk[4];
  #pragma unroll
  for (int w = 0; w < 4; w++){
    const int m = 8 >> w;
    float r = 0.f;
    #pragma unroll
    for (int i = 0; i < 16; i++){
      if (i & m) continue;
      r += ks[i].x*ks[i|m].x + ks[i].y*ks[i|m].y;
    }
    cxk[w] = 2.f * r;
  }

  ws[t]      = gates[t];         // q gates
  ws[64 + t] = gates[128 + t];   // v gates
  if (t < 4) ws[128 + t] = cxk[t];
}

// ============================================================================
// Main kernel: 8 lanes per sample = {q-quad in an even wave, v-quad in the
// next odd wave}. Block 256 threads = 4 waves = 32 samples.
//   waves 0,2: q-circuit -> scores -> RZ half-angles (scr LDS handoff)
//   waves 1,3: v-circuit -> Z-strings, then phases + X-strings + LN/head
// All state shuffles are intra-quad quad_perm DPP (full-rate VALU, no LDS).
// ============================================================================
__global__ __launch_bounds__(256, 1) void qc_main(
    const float* __restrict__ x1,
    const float* __restrict__ pre_w, const float* __restrict__ pre_b,
    const float* __restrict__ gws,
    const float* __restrict__ ln_w, const float* __restrict__ ln_b,
    const float* __restrict__ head_w, const float* __restrict__ head_b,
    float* __restrict__ out, int B){

  __shared__ float pw[4][100];     // pre_w padded (100 % 32 = 4 -> b128-friendly)
  __shared__ float scr[32][9];     // handoff: [sample][2w]=cos, [2w+1]=sin

  const int t    = threadIdx.x;
  const int lane = t & 63;
  const int wid  = t >> 6;                 // 0..3
  const bool qrole = (wid & 1) == 0;
  const int sm   = (wid >> 1) * 16 + (lane >> 2);   // sample in block, 0..31
  const int q    = lane & 3;
  const bool qb0 = (q & 1) != 0;
  const bool qb1 = (q & 2) != 0;
  const int sid  = blockIdx.x * 32 + sm;
  const int sidc = (sid < B) ? sid : (B - 1);       // clamp: keep all lanes active

  // ---- stage pre_w into LDS (96 float4 = full 4x96 matrix) ----
  if (t < 96){
    float4 v = ((const float4*)pre_w)[t];
    int r = t / 24, c4 = (t % 24) * 4;
    pw[r][c4+0] = v.x; pw[r][c4+1] = v.y; pw[r][c4+2] = v.z; pw[r][c4+3] = v.w;
  }
  __syncthreads();

  // ---- x = row @ pre_w.T + pre_b : lane q takes cols [24q, 24q+24) ----
  float xw[4];
  {
    float a0 = 0.f, a1 = 0.f, a2 = 0.f, a3 = 0.f;
    const float4* xrow = (const float4*)(x1 + (size_t)sidc * 96 + 24*q);
    #pragma unroll
    for (int j = 0; j < 6; j++){
      float4 xv = xrow[j];
      const int c = 24*q + 4*j;
      float4 w0 = *(const float4*)&pw[0][c];
      float4 w1 = *(const float4*)&pw[1][c];
      float4 w2 = *(const float4*)&pw[2][c];
      float4 w3 = *(const float4*)&pw[3][c];
      a0 += xv.x*w0.x + xv.y*w0.y + xv.z*w0.z + xv.w*w0.w;
      a1 += xv.x*w1.x + xv.y*w1.y + xv.z*w1.z + xv.w*w1.w;
      a2 += xv.x*w2.x + xv.y*w2.y + xv.z*w2.z + xv.w*w2.w;
      a3 += xv.x*w3.x + xv.y*w3.y + xv.z*w3.z + xv.w*w3.w;
    }
    xw[0] = qred(a0) + pre_b[0];
    xw[1] = qred(a1) + pre_b[1];
    xw[2] = qred(a2) + pre_b[2];
    xw[3] = qred(a3) + pre_b[3];
  }

  float cw[4], sw[4];
  #pragma unroll
  for (int w = 0; w < 4; w++) __sincosf(0.5f*xw[w], &sw[w], &cw[w]);

  const float sgnW0 = qb1 ? -1.f : 1.f;
  const float sgnW1 = qb0 ? -1.f : 1.f;

  c32 a[4];
  build_rx4(a, cw, sw, q, qb0, qb1);

  float o0, o1, o2, o3;           // v-role Z-string outputs (pre-barrier)

  if (qrole){
    // ================= q-circuit =================
    sim4(a, gws, sgnW0, sgnW1, qb0, qb1);

    float p0 = a[0].x*a[0].x + a[0].y*a[0].y;
    float p1 = a[1].x*a[1].x + a[1].y*a[1].y;
    float p2 = a[2].x*a[2].x + a[2].y*a[2].y;
    float p3 = a[3].x*a[3].x + a[3].y*a[3].y;
    float psum = p0 + p1 + p2 + p3;

    // local wires 2,3 (pre-multiply cross terms by 2 to match 2*sx, 2*sy)
    float sz2 = p0 + p1 - p2 - p3;
    float sx2 = 2.f*(a[0].x*a[2].x + a[0].y*a[2].y + a[1].x*a[3].x + a[1].y*a[3].y);
    float sy2 = 2.f*(a[0].x*a[2].y - a[0].y*a[2].x + a[1].x*a[3].y - a[1].y*a[3].x);
    float sz3 = p0 - p1 + p2 - p3;
    float sx3 = 2.f*(a[0].x*a[1].x + a[0].y*a[1].y + a[2].x*a[3].x + a[2].y*a[3].y);
    float sy3 = 2.f*(a[0].x*a[1].y - a[0].y*a[1].x + a[2].x*a[3].y - a[2].y*a[3].x);

    // lane wire 0 (lane^2): symmetric sums give 2*sx / 2*sy after reduce
    c32 r[4];
    #pragma unroll
    for (int k = 0; k < 4; k++){ r[k].x = dppf<DPP_X2>(a[k].x); r[k].y = dppf<DPP_X2>(a[k].y); }
    float sx0 = a[0].x*r[0].x + a[0].y*r[0].y + a[1].x*r[1].x + a[1].y*r[1].y
              + a[2].x*r[2].x + a[2].y*r[2].y + a[3].x*r[3].x + a[3].y*r[3].y;
    float sy0 = (a[0].x*r[0].y - a[0].y*r[0].x + a[1].x*r[1].y - a[1].y*r[1].x
               + a[2].x*r[2].y - a[2].y*r[2].x + a[3].x*r[3].y - a[3].y*r[3].x) * sgnW0;
    float sz0 = sgnW0 * psum;

    // lane wire 1 (lane^1)
    #pragma unroll
    for (int k = 0; k < 4; k++){ r[k].x = dppf<DPP_X1>(a[k].x); r[k].y = dppf<DPP_X1>(a[k].y); }
    float sx1 = a[0].x*r[0].x + a[0].y*r[0].y + a[1].x*r[1].x + a[1].y*r[1].y
              + a[2].x*r[2].x + a[2].y*r[2].y + a[3].x*r[3].x + a[3].y*r[3].y;
    float sy1 = (a[0].x*r[0].y - a[0].y*r[0].x + a[1].x*r[1].y - a[1].y*r[1].x
               + a[2].x*r[2].y - a[2].y*r[2].x + a[3].x*r[3].y - a[3].y*r[3].x) * sgnW1;
    float sz1 = sgnW1 * psum;

    sz0 = qred(sz0); sx0 = qred(sx0); sy0 = qred(sy0);
    sz1 = qred(sz1); sx1 = qred(sx1); sy1 = qred(sy1);
    sz2 = qred(sz2); sx2 = qred(sx2); sy2 = qred(sy2);
    sz3 = qred(sz3); sx3 = qred(sx3); sy3 = qred(sy3);

    // lane q handles wire q
    float szq = sel4(qb0, qb1, sz0, sz1, sz2, sz3);
    float sxq = sel4(qb0, qb1, sx0, sx1, sx2, sx3);
    float syq = sel4(qb0, qb1, sy0, sy1, sy2, sy3);
    float swq = sel4(qb0, qb1, sw[0], sw[1], sw[2], sw[3]);
    float cwq = sel4(qb0, qb1, cw[0], cw[1], cw[2], cw[3]);
    float cxkq = sel4(qb0, qb1, gws[128], gws[129], gws[130], gws[131]);

    float cth = 1.f - 2.f*swq*swq;
    float sth = 2.f*swq*cwq;
    float z   = cth*szq + sth*syq;
    float xm  = sxq * cxkq;
    float score = sqrtf(z*z + xm*xm);
    float th = fast_tanh(score) * PI_F;
    float srv, crv; __sincosf(0.5f*th, &srv, &crv);
    scr[sm][2*q]     = crv;
    scr[sm][2*q + 1] = srv;
  } else {
    // ================= v-circuit (pre-barrier) =================
    sim4(a, gws + 64, sgnW0, sgnW1, qb0, qb1);

    float p0 = a[0].x*a[0].x + a[0].y*a[0].y;
    float p1 = a[1].x*a[1].x + a[1].y*a[1].y;
    float p2 = a[2].x*a[2].x + a[2].y*a[2].y;
    float p3 = a[3].x*a[3].x + a[3].y*a[3].y;
    float psum = p0 + p1 + p2 + p3;
    float sgn01 = sgnW0 * sgnW1;
    // Z-strings zm = {8,12,14,15}; RZ phases cancel in |amp|^2
    o0 = qred(sgnW0 * psum);
    o1 = qred(sgn01 * psum);
    o2 = qred(sgn01 * (p0 + p1 - p2 - p3));
    o3 = qred(sgn01 * (p0 - p1 - p2 + p3));
  }

  __syncthreads();   // scr handoff; q-waves are done after this

  if (!qrole){
    float c0 = scr[sm][0], s0 = scr[sm][1];
    float c1 = scr[sm][2], s1 = scr[sm][3];
    float c2 = scr[sm][4], s2 = scr[sm][5];
    float c3 = scr[sm][6], s3 = scr[sm][7];

    // RZ phase factors: ph01[q] (per-lane scalar) * ph23[k]
    float c01m = c0*c1 - s0*s1, c01p = c0*c1 + s0*s1;
    float s01p = c0*s1 + s0*c1, s01m = c0*s1 - s0*c1;
    bool selq = qb0 != qb1;
    float phx = selq ? c01p : c01m;
    float phm = selq ? s01m : s01p;
    float phy = qb0 ? phm : -phm;
    float c23m = c2*c3 - s2*s3, c23p = c2*c3 + s2*s3;
    float s23p = c2*s3 + s2*c3, s23m = c2*s3 - s2*c3;
    c32 P[4] = { {c23m, -s23p}, {c23p, s23m}, {c23p, -s23m}, {c23m, s23p} };
    #pragma unroll
    for (int k = 0; k < 4; k++){
      c32 b = { a[k].x*phx - a[k].y*phy, a[k].x*phy + a[k].y*phx };
      a[k].x = b.x*P[k].x - b.y*P[k].y;
      a[k].y = b.x*P[k].y + b.y*P[k].x;
    }

    // X-strings, masks {12,6,3,1}: symmetric all-lane sums = 2*r directly
    c32 r[4];
    #pragma unroll
    for (int k = 0; k < 4; k++){ r[k].x = dppf<DPP_X3>(a[k].x); r[k].y = dppf<DPP_X3>(a[k].y); }
    float s4 = a[0].x*r[0].x + a[0].y*r[0].y + a[1].x*r[1].x + a[1].y*r[1].y
             + a[2].x*r[2].x + a[2].y*r[2].y + a[3].x*r[3].x + a[3].y*r[3].y;
    #pragma unroll
    for (int k = 0; k < 4; k++){ r[k].x = dppf<DPP_X1>(a[k].x); r[k].y = dppf<DPP_X1>(a[k].y); }
    float s5 = a[0].x*r[2].x + a[0].y*r[2].y + a[1].x*r[3].x + a[1].y*r[3].y
             + a[2].x*r[0].x + a[2].y*r[0].y + a[3].x*r[1].x + a[3].y*r[1].y;
    float s6 = 2.f*(a[0].x*a[3].x + a[0].y*a[3].y + a[1].x*a[2].x + a[1].y*a[2].y);
    float s7 = 2.f*(a[0].x*a[1].x + a[0].y*a[1].y + a[2].x*a[3].x + a[2].y*a[3].y);
    float o4 = qred(s4), o5 = qred(s5), o6 = qred(s6), o7 = qred(s7);

    // ---- LayerNorm(8) -> tanh-GELU -> head (duplicated across the quad) ----
    float o[8] = { o0, o1, o2, o3, o4, o5, o6, o7 };
    float mu = 0.f;
    #pragma unroll
    for (int j = 0; j < 8; j++) mu += o[j];
    mu *= 0.125f;
    float var = 0.f;
    #pragma unroll
    for (int j = 0; j < 8; j++){ float d = o[j] - mu; var += d*d; }
    var *= 0.125f;
    float inv = rsqrtf(var + 1e-5f);
    float h0 = head_b[0], h1 = head_b[1];
    #pragma unroll
    for (int j = 0; j < 8; j++){
      float y = (o[j] - mu) * inv * ln_w[j] + ln_b[j];
      float u = 0.7978845608f * (y + 0.044715f*y*y*y);
      float g = 0.5f * y * (1.f + fast_tanh(u));
      h0 += g * head_w[j];
      h1 += g * head_w[8 + j];
    }

    if (q == 0 && sid < B){
      float2 r2; r2.x = h0; r2.y = h1;
      ((float2*)out)[sid] = r2;
    }
  }
}

extern "C" void kernel_launch(void* const* d_in, const int* in_sizes, int n_in,
                              void* d_out, int out_size, void* d_ws, size_t ws_size,
                              hipStream_t stream) {
  const float* x1     = (const float*)d_in[0];
  const float* pre_w  = (const float*)d_in[1];
  const float* pre_b  = (const float*)d_in[2];
  const float* q_rot  = (const float*)d_in[3];
  const float* k_rot  = (const float*)d_in[4];
  const float* v_rot  = (const float*)d_in[5];
  const float* q_crx  = (const float*)d_in[6];
  const float* k_crx  = (const float*)d_in[7];
  const float* v_crx  = (const float*)d_in[8];
  const float* ln_w   = (const float*)d_in[9];
  const float* ln_b   = (const float*)d_in[10];
  const float* head_w = (const float*)d_in[11];
  const float* head_b = (const float*)d_in[12];
  float* out = (float*)d_out;
  float* ws  = (float*)d_ws;
  (void)ws_size; (void)n_in; (void)out_size;

  const int B = in_sizes[0] / 96;
  const int nb = (B + 31) / 32;

  qc_setup<<<1, 64, 0, stream>>>(q_rot, k_rot, v_rot, q_crx, k_crx, v_crx, ws);
  qc_main<<<nb, 256, 0, stream>>>(x1, pre_w, pre_b, ws,
                                  ln_w, ln_b, head_w, head_b, out, B);
}

// Round 3
// 86.326 us; speedup vs baseline: 1.1836x; 1.0353x over previous
//
#include <hip/hip_runtime.h>
#include <math.h>

#define PI_F 3.14159265358979323846f

struct c32 { float x, y; };

// ---------------------------------------------------------------------------
// quad-lane DPP helpers (all cross-lane traffic is intra-quad quad_perm DPP)
// ---------------------------------------------------------------------------
#define DPP_X1 0xB1   // quad_perm [1,0,3,2]  lane ^ 1
#define DPP_X2 0x4E   // quad_perm [2,3,0,1]  lane ^ 2
#define DPP_X3 0x1B   // quad_perm [3,2,1,0]  lane ^ 3

template<int CTRL>
__device__ __forceinline__ float dppf(float v){
  return __int_as_float(__builtin_amdgcn_update_dpp(
      0, __float_as_int(v), CTRL, 0xF, 0xF, true));
}

__device__ __forceinline__ float qred(float v){   // quad butterfly sum
  v += dppf<DPP_X1>(v);
  v += dppf<DPP_X2>(v);
  return v;
}

__device__ __forceinline__ float sel4(bool b0, bool b1,
                                      float v0, float v1, float v2, float v3){
  float lo = b0 ? v1 : v0;
  float hi = b0 ? v3 : v2;
  return b1 ? hi : lo;
}

__device__ __forceinline__ float fast_tanh(float x){
  float e = __expf(2.f * x);
  return 1.f - 2.f * __builtin_amdgcn_rcpf(e + 1.f);
}

// ---------------------------------------------------------------------------
// 4-qubit state split across a quad: lane q (= lane&3) holds amps (q<<2)|k,
// k = 0..3.  Wire w -> amp-index bit (3-w):
//   wire0 -> q bit1 (lane^2), wire1 -> q bit0 (lane^1),
//   wire2 -> k bit1 (local),  wire3 -> k bit0 (local)
// ---------------------------------------------------------------------------

// Rot [[A, -conj(C)],[C, conj(A)]] on a lane wire.
template<int XM>
__device__ __forceinline__ void rot_lane(c32* a, float Ax, float Ay,
                                         float Cx, float Cy, float sgn){
  c32 r[4];
  #pragma unroll
  for (int k = 0; k < 4; k++){ r[k].x = dppf<XM>(a[k].x); r[k].y = dppf<XM>(a[k].y); }
  float Py = Ay * sgn, Qx = -Cx * sgn;
  #pragma unroll
  for (int k = 0; k < 4; k++){
    float nx = Ax*a[k].x - Py*a[k].y + Qx*r[k].x - Cy*r[k].y;
    float ny = Ax*a[k].y + Py*a[k].x + Qx*r[k].y + Cy*r[k].x;
    a[k].x = nx; a[k].y = ny;
  }
}

// Rot on a local wire (pairs (k, k|MB))
template<int MB>
__device__ __forceinline__ void rot_local(c32* a, float Ax, float Ay,
                                          float Cx, float Cy){
  #pragma unroll
  for (int k = 0; k < 4; k++){
    if (k & MB) continue;
    c32 u = a[k], v = a[k|MB];
    a[k].x    = Ax*u.x - Ay*u.y - Cx*v.x - Cy*v.y;
    a[k].y    = Ax*u.y + Ay*u.x - Cx*v.y + Cy*v.x;
    a[k|MB].x = Cx*u.x - Cy*u.y + Ax*v.x + Ay*v.y;
    a[k|MB].y = Cx*u.y + Cy*u.x + Ax*v.y - Ay*v.x;
  }
}

// fused CRX+CNOT primitive: each slot <- c*other + sn*(own.y, -own.x)
__device__ __forceinline__ void crx_pair(c32& u, c32& v, float c, float sn){
  c32 uo = u, vo = v;
  u.x = c*vo.x + sn*uo.y;  u.y = c*vo.y - sn*uo.x;
  v.x = c*uo.x + sn*vo.y;  v.y = c*uo.y - sn*vo.x;
}

// control on lane wire (active per lane), target local: pairs k <-> k^KM
template<int KM>
__device__ __forceinline__ void crx_lanectl_local(c32* a, float c, float sn, bool act){
  c32 n[4];
  #pragma unroll
  for (int k = 0; k < 4; k++){
    n[k].x = c*a[k^KM].x + sn*a[k].y;
    n[k].y = c*a[k^KM].y - sn*a[k].x;
  }
  #pragma unroll
  for (int k = 0; k < 4; k++){
    a[k].x = act ? n[k].x : a[k].x;
    a[k].y = act ? n[k].y : a[k].y;
  }
}

// control on local wire (amps K0,K1 of every lane), target lane wire XM
template<int XM, int K0, int K1>
__device__ __forceinline__ void crx_localctl_lane(c32* a, float c, float sn){
  float rx0 = dppf<XM>(a[K0].x), ry0 = dppf<XM>(a[K0].y);
  float rx1 = dppf<XM>(a[K1].x), ry1 = dppf<XM>(a[K1].y);
  float u0x = a[K0].x, u0y = a[K0].y, u1x = a[K1].x, u1y = a[K1].y;
  a[K0].x = c*rx0 + sn*u0y;  a[K0].y = c*ry0 - sn*u0x;
  a[K1].x = c*rx1 + sn*u1y;  a[K1].y = c*ry1 - sn*u1x;
}

// control and target both lane wires
template<int XM>
__device__ __forceinline__ void crx_lane_lane(c32* a, float c, float sn, bool act){
  #pragma unroll
  for (int k = 0; k < 4; k++){
    float rx = dppf<XM>(a[k].x), ry = dppf<XM>(a[k].y);
    float nx = c*rx + sn*a[k].y;
    float ny = c*ry - sn*a[k].x;
    a[k].x = act ? nx : a[k].x;
    a[k].y = act ? ny : a[k].y;
  }
}

// full initQKV ladder; gp = 8 gates x 8 floats {Ax,Ay,Cx,Cy,c,s,_,_}
// pairs: (0,1)(1,2)(2,3)(3,0)(0,3)(1,0)(2,1)(3,2)
__device__ __forceinline__ void sim4(c32* a, const float* gp,
                                     float sgnW0, float sgnW1, bool qb0, bool qb1){
  rot_lane<DPP_X2>(a, gp[0],  gp[1],  gp[2],  gp[3],  sgnW0);   // Rot w0
  crx_lane_lane<DPP_X1>(a, gp[4], gp[5], qb1);                  // CRX(0,1)
  rot_lane<DPP_X1>(a, gp[8],  gp[9],  gp[10], gp[11], sgnW1);   // Rot w1
  crx_lanectl_local<2>(a, gp[12], gp[13], qb0);                 // CRX(1,2)
  rot_local<2>(a, gp[16], gp[17], gp[18], gp[19]);              // Rot w2
  crx_pair(a[2], a[3], gp[20], gp[21]);                         // CRX(2,3)
  rot_local<1>(a, gp[24], gp[25], gp[26], gp[27]);              // Rot w3
  crx_localctl_lane<DPP_X2,1,3>(a, gp[28], gp[29]);             // CRX(3,0)
  rot_lane<DPP_X2>(a, gp[32], gp[33], gp[34], gp[35], sgnW0);   // Rot w0
  crx_lanectl_local<1>(a, gp[36], gp[37], qb1);                 // CRX(0,3)
  rot_lane<DPP_X1>(a, gp[40], gp[41], gp[42], gp[43], sgnW1);   // Rot w1
  crx_lane_lane<DPP_X2>(a, gp[44], gp[45], qb0);                // CRX(1,0)
  rot_local<2>(a, gp[48], gp[49], gp[50], gp[51]);              // Rot w2
  crx_localctl_lane<DPP_X1,2,3>(a, gp[52], gp[53]);             // CRX(2,1)
  rot_local<1>(a, gp[56], gp[57], gp[58], gp[59]);              // Rot w3
  crx_pair(a[1], a[3], gp[60], gp[61]);                         // CRX(3,2)
}

// RX(x)|0000> product state, per-lane slice: amp = mag * (-i)^popc(i)
__device__ __forceinline__ void build_rx4(c32* a, const float* cw, const float* sw,
                                          int q, bool qb0, bool qb1){
  float m01 = (qb1 ? sw[0] : cw[0]) * (qb0 ? sw[1] : cw[1]);
  float g0 = m01 * (cw[2]*cw[3]);
  float g1 = m01 * (cw[2]*sw[3]);
  float g2 = m01 * (sw[2]*cw[3]);
  float g3 = m01 * (sw[2]*sw[3]);
  float bx = (q == 0) ? 1.f : (q == 3) ? -1.f : 0.f;
  float by = (q == 1 || q == 2) ? -1.f : 0.f;
  a[0].x =  g0*bx;  a[0].y =  g0*by;   // k=0: *1
  a[1].x =  g1*by;  a[1].y = -g1*bx;   // k=1: *(-i)
  a[2].x =  g2*by;  a[2].y = -g2*bx;   // k=2: *(-i)
  a[3].x = -g3*bx;  a[3].y = -g3*by;   // k=3: *(-1)
}

// ============================================================================
// Single fused kernel. Block = 256 threads = 4 waves = 32 samples
// (8 lanes/sample: q-quad in an even wave, v-quad in the next odd wave).
// Per-block cooperative setup (no second dispatch, no d_ws):
//   phase A: stage pre_w (t<96); gate matrices q/k/v by t in [96,120);
//            every thread issues its x-row loads.
//   phase B: dot + sincos + build_rx (all threads).
//   phase C: q-waves: q-sim + expectations, then the batch-uniform k-sim
//            (redundant per q-wave, uniform across lanes -> no divergence,
//            no handoff barrier) -> cxk -> scores -> scr.
//            v-waves: v-sim + Z-strings.
//   barrier; phase D: v-waves: RZ phases + X-strings + LN/GELU/head + store.
// ============================================================================
__global__ __launch_bounds__(256, 1) void qc_main(
    const float* __restrict__ x1,
    const float* __restrict__ pre_w, const float* __restrict__ pre_b,
    const float* __restrict__ q_rot, const float* __restrict__ k_rot,
    const float* __restrict__ v_rot,
    const float* __restrict__ q_crx, const float* __restrict__ k_crx,
    const float* __restrict__ v_crx,
    const float* __restrict__ ln_w, const float* __restrict__ ln_b,
    const float* __restrict__ head_w, const float* __restrict__ head_b,
    float* __restrict__ out, int B){

  __shared__ float pw[4][100];     // pre_w padded (100 % 32 = 4)
  __shared__ float gl[192];        // [0..63] q, [64..127] k, [128..191] v gates
  __shared__ float scr[32][9];     // handoff: [sample][2w]=cos, [2w+1]=sin

  const int t    = threadIdx.x;
  const int lane = t & 63;
  const int wid  = t >> 6;                 // 0..3
  const bool qrole = (wid & 1) == 0;
  const int sm   = (wid >> 1) * 16 + (lane >> 2);   // sample in block, 0..31
  const int q    = lane & 3;
  const bool qb0 = (q & 1) != 0;
  const bool qb1 = (q & 2) != 0;
  const int sid  = blockIdx.x * 32 + sm;
  const int sidc = (sid < B) ? sid : (B - 1);       // clamp: keep lanes active

  // ---- phase A: issue x-row loads early (latency hidden under setup) ----
  float4 xr[6];
  {
    const float4* xrow = (const float4*)(x1 + (size_t)sidc * 96 + 24*q);
    #pragma unroll
    for (int j = 0; j < 6; j++) xr[j] = xrow[j];
  }

  // stage pre_w into LDS (96 float4 = full 4x96 matrix)
  if (t < 96){
    float4 v = ((const float4*)pre_w)[t];
    int r = t / 24, c4 = (t % 24) * 4;
    pw[r][c4+0] = v.x; pw[r][c4+1] = v.y; pw[r][c4+2] = v.z; pw[r][c4+3] = v.w;
  }

  // gate matrices: threads 96..119, one gate each (grp 0=q, 1=k, 2=v)
  if (t >= 96 && t < 120){
    const int u = t - 96;
    const int grp = u >> 3, g = u & 7;
    const float* rotp = grp == 0 ? q_rot : (grp == 1 ? k_rot : v_rot);
    const float* crxp = grp == 0 ? q_crx : (grp == 1 ? k_crx : v_crx);
    float phi = rotp[3*g], th = rotp[3*g+1], om = rotp[3*g+2];
    float c, s, ca, sa, cb, sb;
    __sincosf(0.5f*th,       &s,  &c);
    __sincosf(0.5f*(phi+om), &sa, &ca);
    __sincosf(0.5f*(phi-om), &sb, &cb);
    float cc, cs; __sincosf(0.5f*crxp[g], &cs, &cc);
    float* dst = &gl[64*grp + 8*g];
    dst[0] = c*ca; dst[1] = -c*sa; dst[2] = s*cb; dst[3] = -s*sb;
    dst[4] = cc;   dst[5] = cs;
    dst[6] = 0.f;  dst[7] = 0.f;
  }
  __syncthreads();

  // ---- phase B: x = row @ pre_w.T + pre_b : lane q takes cols [24q,24q+24) ----
  float xw[4];
  {
    float a0 = 0.f, a1 = 0.f, a2 = 0.f, a3 = 0.f;
    #pragma unroll
    for (int j = 0; j < 6; j++){
      float4 xv = xr[j];
      const int c = 24*q + 4*j;
      float4 w0 = *(const float4*)&pw[0][c];
      float4 w1 = *(const float4*)&pw[1][c];
      float4 w2 = *(const float4*)&pw[2][c];
      float4 w3 = *(const float4*)&pw[3][c];
      a0 += xv.x*w0.x + xv.y*w0.y + xv.z*w0.z + xv.w*w0.w;
      a1 += xv.x*w1.x + xv.y*w1.y + xv.z*w1.z + xv.w*w1.w;
      a2 += xv.x*w2.x + xv.y*w2.y + xv.z*w2.z + xv.w*w2.w;
      a3 += xv.x*w3.x + xv.y*w3.y + xv.z*w3.z + xv.w*w3.w;
    }
    xw[0] = qred(a0) + pre_b[0];
    xw[1] = qred(a1) + pre_b[1];
    xw[2] = qred(a2) + pre_b[2];
    xw[3] = qred(a3) + pre_b[3];
  }

  float cw[4], sw[4];
  #pragma unroll
  for (int w = 0; w < 4; w++) __sincosf(0.5f*xw[w], &sw[w], &cw[w]);

  const float sgnW0 = qb1 ? -1.f : 1.f;
  const float sgnW1 = qb0 ? -1.f : 1.f;

  c32 a[4];
  build_rx4(a, cw, sw, q, qb0, qb1);

  float o0, o1, o2, o3;           // v-role Z-string outputs (pre-barrier)

  if (qrole){
    // ================= q-circuit =================
    sim4(a, &gl[0], sgnW0, sgnW1, qb0, qb1);

    float p0 = a[0].x*a[0].x + a[0].y*a[0].y;
    float p1 = a[1].x*a[1].x + a[1].y*a[1].y;
    float p2 = a[2].x*a[2].x + a[2].y*a[2].y;
    float p3 = a[3].x*a[3].x + a[3].y*a[3].y;
    float psum = p0 + p1 + p2 + p3;

    float sz2 = p0 + p1 - p2 - p3;
    float sx2 = 2.f*(a[0].x*a[2].x + a[0].y*a[2].y + a[1].x*a[3].x + a[1].y*a[3].y);
    float sy2 = 2.f*(a[0].x*a[2].y - a[0].y*a[2].x + a[1].x*a[3].y - a[1].y*a[3].x);
    float sz3 = p0 - p1 + p2 - p3;
    float sx3 = 2.f*(a[0].x*a[1].x + a[0].y*a[1].y + a[2].x*a[3].x + a[2].y*a[3].y);
    float sy3 = 2.f*(a[0].x*a[1].y - a[0].y*a[1].x + a[2].x*a[3].y - a[2].y*a[3].x);

    c32 r[4];
    #pragma unroll
    for (int k = 0; k < 4; k++){ r[k].x = dppf<DPP_X2>(a[k].x); r[k].y = dppf<DPP_X2>(a[k].y); }
    float sx0 = a[0].x*r[0].x + a[0].y*r[0].y + a[1].x*r[1].x + a[1].y*r[1].y
              + a[2].x*r[2].x + a[2].y*r[2].y + a[3].x*r[3].x + a[3].y*r[3].y;
    float sy0 = (a[0].x*r[0].y - a[0].y*r[0].x + a[1].x*r[1].y - a[1].y*r[1].x
               + a[2].x*r[2].y - a[2].y*r[2].x + a[3].x*r[3].y - a[3].y*r[3].x) * sgnW0;
    float sz0 = sgnW0 * psum;

    #pragma unroll
    for (int k = 0; k < 4; k++){ r[k].x = dppf<DPP_X1>(a[k].x); r[k].y = dppf<DPP_X1>(a[k].y); }
    float sx1 = a[0].x*r[0].x + a[0].y*r[0].y + a[1].x*r[1].x + a[1].y*r[1].y
              + a[2].x*r[2].x + a[2].y*r[2].y + a[3].x*r[3].x + a[3].y*r[3].y;
    float sy1 = (a[0].x*r[0].y - a[0].y*r[0].x + a[1].x*r[1].y - a[1].y*r[1].x
               + a[2].x*r[2].y - a[2].y*r[2].x + a[3].x*r[3].y - a[3].y*r[3].x) * sgnW1;
    float sz1 = sgnW1 * psum;

    sz0 = qred(sz0); sx0 = qred(sx0); sy0 = qred(sy0);
    sz1 = qred(sz1); sx1 = qred(sx1); sy1 = qred(sy1);
    sz2 = qred(sz2); sx2 = qred(sx2); sy2 = qred(sy2);
    sz3 = qred(sz3); sx3 = qred(sx3); sy3 = qred(sy3);

    float szq = sel4(qb0, qb1, sz0, sz1, sz2, sz3);
    float sxq = sel4(qb0, qb1, sx0, sx1, sx2, sx3);
    float syq = sel4(qb0, qb1, sy0, sy1, sy2, sy3);
    float swq = sel4(qb0, qb1, sw[0], sw[1], sw[2], sw[3]);
    float cwq = sel4(qb0, qb1, cw[0], cw[1], cw[2], cw[3]);

    // ===== batch-uniform k-circuit: U_k|0000>, wave-redundant, no handoff =====
    c32 b[4];
    b[0].x = (q == 0) ? 1.f : 0.f; b[0].y = 0.f;
    b[1].x = 0.f; b[1].y = 0.f;
    b[2].x = 0.f; b[2].y = 0.f;
    b[3].x = 0.f; b[3].y = 0.f;
    sim4(b, &gl[64], sgnW0, sgnW1, qb0, qb1);

    float kx2 = 2.f*(b[0].x*b[2].x + b[0].y*b[2].y + b[1].x*b[3].x + b[1].y*b[3].y);
    float kx3 = 2.f*(b[0].x*b[1].x + b[0].y*b[1].y + b[2].x*b[3].x + b[2].y*b[3].y);
    #pragma unroll
    for (int k = 0; k < 4; k++){ r[k].x = dppf<DPP_X2>(b[k].x); r[k].y = dppf<DPP_X2>(b[k].y); }
    float kx0 = b[0].x*r[0].x + b[0].y*r[0].y + b[1].x*r[1].x + b[1].y*r[1].y
              + b[2].x*r[2].x + b[2].y*r[2].y + b[3].x*r[3].x + b[3].y*r[3].y;
    #pragma unroll
    for (int k = 0; k < 4; k++){ r[k].x = dppf<DPP_X1>(b[k].x); r[k].y = dppf<DPP_X1>(b[k].y); }
    float kx1 = b[0].x*r[0].x + b[0].y*r[0].y + b[1].x*r[1].x + b[1].y*r[1].y
              + b[2].x*r[2].x + b[2].y*r[2].y + b[3].x*r[3].x + b[3].y*r[3].y;
    kx0 = qred(kx0); kx1 = qred(kx1); kx2 = qred(kx2); kx3 = qred(kx3);
    float cxkq = sel4(qb0, qb1, kx0, kx1, kx2, kx3);

    // ===== score -> RZ half-angles =====
    float cth = 1.f - 2.f*swq*swq;
    float sth = 2.f*swq*cwq;
    float z   = cth*szq + sth*syq;
    float xm  = sxq * cxkq;
    float score = sqrtf(z*z + xm*xm);
    float th = fast_tanh(score) * PI_F;
    float srv, crv; __sincosf(0.5f*th, &srv, &crv);
    scr[sm][2*q]     = crv;
    scr[sm][2*q + 1] = srv;
  } else {
    // ================= v-circuit (pre-barrier) =================
    sim4(a, &gl[128], sgnW0, sgnW1, qb0, qb1);

    float p0 = a[0].x*a[0].x + a[0].y*a[0].y;
    float p1 = a[1].x*a[1].x + a[1].y*a[1].y;
    float p2 = a[2].x*a[2].x + a[2].y*a[2].y;
    float p3 = a[3].x*a[3].x + a[3].y*a[3].y;
    float psum = p0 + p1 + p2 + p3;
    float sgn01 = sgnW0 * sgnW1;
    o0 = qred(sgnW0 * psum);
    o1 = qred(sgn01 * psum);
    o2 = qred(sgn01 * (p0 + p1 - p2 - p3));
    o3 = qred(sgn01 * (p0 - p1 - p2 + p3));
  }

  __syncthreads();   // scr handoff; q-waves are done after this

  if (!qrole){
    float c0 = scr[sm][0], s0 = scr[sm][1];
    float c1 = scr[sm][2], s1 = scr[sm][3];
    float c2 = scr[sm][4], s2 = scr[sm][5];
    float c3 = scr[sm][6], s3 = scr[sm][7];

    float c01m = c0*c1 - s0*s1, c01p = c0*c1 + s0*s1;
    float s01p = c0*s1 + s0*c1, s01m = c0*s1 - s0*c1;
    bool selq = qb0 != qb1;
    float phx = selq ? c01p : c01m;
    float phm = selq ? s01m : s01p;
    float phy = qb0 ? phm : -phm;
    float c23m = c2*c3 - s2*s3, c23p = c2*c3 + s2*s3;
    float s23p = c2*s3 + s2*c3, s23m = c2*s3 - s2*c3;
    c32 P[4] = { {c23m, -s23p}, {c23p, s23m}, {c23p, -s23m}, {c23m, s23p} };
    #pragma unroll
    for (int k = 0; k < 4; k++){
      c32 bb = { a[k].x*phx - a[k].y*phy, a[k].x*phy + a[k].y*phx };
      a[k].x = bb.x*P[k].x - bb.y*P[k].y;
      a[k].y = bb.x*P[k].y + bb.y*P[k].x;
    }

    // X-strings, masks {12,6,3,1}
    c32 r[4];
    #pragma unroll
    for (int k = 0; k < 4; k++){ r[k].x = dppf<DPP_X3>(a[k].x); r[k].y = dppf<DPP_X3>(a[k].y); }
    float s4 = a[0].x*r[0].x + a[0].y*r[0].y + a[1].x*r[1].x + a[1].y*r[1].y
             + a[2].x*r[2].x + a[2].y*r[2].y + a[3].x*r[3].x + a[3].y*r[3].y;
    #pragma unroll
    for (int k = 0; k < 4; k++){ r[k].x = dppf<DPP_X1>(a[k].x); r[k].y = dppf<DPP_X1>(a[k].y); }
    float s5 = a[0].x*r[2].x + a[0].y*r[2].y + a[1].x*r[3].x + a[1].y*r[3].y
             + a[2].x*r[0].x + a[2].y*r[0].y + a[3].x*r[1].x + a[3].y*r[1].y;
    float s6 = 2.f*(a[0].x*a[3].x + a[0].y*a[3].y + a[1].x*a[2].x + a[1].y*a[2].y);
    float s7 = 2.f*(a[0].x*a[1].x + a[0].y*a[1].y + a[2].x*a[3].x + a[2].y*a[3].y);
    float o4 = qred(s4), o5 = qred(s5), o6 = qred(s6), o7 = qred(s7);

    // ---- LayerNorm(8) -> GELU -> head (duplicated across the quad) ----
    float o[8] = { o0, o1, o2, o3, o4, o5, o6, o7 };
    float mu = 0.f;
    #pragma unroll
    for (int j = 0; j < 8; j++) mu += o[j];
    mu *= 0.125f;
    float var = 0.f;
    #pragma unroll
    for (int j = 0; j < 8; j++){ float d = o[j] - mu; var += d*d; }
    var *= 0.125f;
    float inv = rsqrtf(var + 1e-5f);
    float h0 = head_b[0], h1 = head_b[1];
    #pragma unroll
    for (int j = 0; j < 8; j++){
      float y = (o[j] - mu) * inv * ln_w[j] + ln_b[j];
      float u = 0.7978845608f * (y + 0.044715f*y*y*y);
      float g = 0.5f * y * (1.f + fast_tanh(u));
      h0 += g * head_w[j];
      h1 += g * head_w[8 + j];
    }

    if (q == 0 && sid < B){
      float2 r2; r2.x = h0; r2.y = h1;
      ((float2*)out)[sid] = r2;
    }
  }
}

extern "C" void kernel_launch(void* const* d_in, const int* in_sizes, int n_in,
                              void* d_out, int out_size, void* d_ws, size_t ws_size,
                              hipStream_t stream) {
  const float* x1     = (const float*)d_in[0];
  const float* pre_w  = (const float*)d_in[1];
  const float* pre_b  = (const float*)d_in[2];
  const float* q_rot  = (const float*)d_in[3];
  const float* k_rot  = (const float*)d_in[4];
  const float* v_rot  = (const float*)d_in[5];
  const float* q_crx  = (const float*)d_in[6];
  const float* k_crx  = (const float*)d_in[7];
  const float* v_crx  = (const float*)d_in[8];
  const float* ln_w   = (const float*)d_in[9];
  const float* ln_b   = (const float*)d_in[10];
  const float* head_w = (const float*)d_in[11];
  const float* head_b = (const float*)d_in[12];
  float* out = (float*)d_out;
  (void)d_ws; (void)ws_size; (void)n_in; (void)out_size;

  const int B = in_sizes[0] / 96;
  const int nb = (B + 31) / 32;

  qc_main<<<nb, 256, 0, stream>>>(x1, pre_w, pre_b,
                                  q_rot, k_rot, v_rot, q_crx, k_crx, v_crx,
                                  ln_w, ln_b, head_w, head_b, out, B);
}